// Round 1
// 622.675 us; speedup vs baseline: 1.4115x; 1.4115x over previous
//
#include <hip/hip_runtime.h>
#include <hip/hip_bf16.h>
#include <math.h>

// ---------------------------------------------------------------------------
// WindowAttention (dual-lambda linear attention) for MI355X / gfx950
//   B=2048, N=64 tokens, C=384, H=12 heads, d=32
//   Pipeline: setup (weight repack bf16 + lambda) -> qkv+attention fused
//             -> output projection GEMM
//   This revision: 2-batch 512-thread blocks, async global_load_lds weight
//   staging (XOR-swizzled source, linear LDS dest), 1 barrier/K-chunk,
//   conflict-free transposed fk/fv epilogue, XCD-swizzled proj GEMM.
// ---------------------------------------------------------------------------

typedef __attribute__((ext_vector_type(8))) short short8;   // 8 x bf16
typedef __attribute__((ext_vector_type(4))) float f32x4;
typedef __attribute__((ext_vector_type(4))) unsigned short us4;

typedef const __attribute__((address_space(1))) unsigned int gu32c;
typedef __attribute__((address_space(3))) unsigned int lu32;

#define MFMA_BF16(A,B,C) __builtin_amdgcn_mfma_f32_16x16x32_bf16(A,B,C,0,0,0)

__device__ __forceinline__ unsigned short f2bf(float f) {
  unsigned int u = __float_as_uint(f);
  u += 0x7FFFu + ((u >> 16) & 1u);            // round-to-nearest-even
  return (unsigned short)(u >> 16);
}

#define BB 2048
#define NN 64
#define CC 384
#define HH 12
#define DD 32

// workspace byte offsets (total ~101.9 MB)
#define WS_O    0                         // bf16 [131072][384]  = 100663296 B
#define WS_WT   100663296                 // bf16 [12][96][384]  =    884736 B
#define WS_W2T  101548032                 // bf16 [384][384]     =    294912 B
#define WS_WB   101842944                 // f32  [12][96]       =      4608 B
#define WS_LAM  101847552                 // f32  [12]           =        48 B

// ---------------------------------------------------------------------------
// setup: repack qkv_w -> WT[h][c][k] (c: 0-31 q, 32-63 k, 64-95 v),
//        proj_w -> W2T[n][k], biases -> Wb[h][c], lamS[h] = 1 - lambda_full
// ---------------------------------------------------------------------------
__global__ void setup_kernel(const float* __restrict__ qkv_w,
                             const float* __restrict__ qkv_b,
                             const float* __restrict__ proj_w,
                             const float* __restrict__ lk1, const float* __restrict__ lv1,
                             const float* __restrict__ lk2, const float* __restrict__ lv2,
                             unsigned short* __restrict__ WT,
                             unsigned short* __restrict__ W2T,
                             float* __restrict__ Wb,
                             float* __restrict__ lamS)
{
  const int nWT  = HH * 96 * CC;   // 442368
  const int nW2T = CC * CC;        // 147456
  const int nWb  = HH * 96;        // 1152
  int gid = blockIdx.x * 256 + threadIdx.x;
  if (gid < nWT) {
    int h = gid / (96 * CC);
    int r = gid % (96 * CC);
    int c = r / CC;
    int k = r % CC;
    int col = (c >> 5) * CC + h * DD + (c & 31);      // q/k/v block, head, dim
    WT[gid] = f2bf(qkv_w[(size_t)k * (3 * CC) + col]);
  } else if (gid < nWT + nW2T) {
    int j = gid - nWT;
    int n = j / CC, k = j % CC;
    W2T[j] = f2bf(proj_w[(size_t)k * CC + n]);
  } else if (gid < nWT + nW2T + nWb) {
    int j = gid - nWT - nW2T;
    int h = j / 96, c = j % 96;
    Wb[j] = qkv_b[(c >> 5) * CC + h * DD + (c & 31)];
  } else if (gid < nWT + nW2T + nWb + HH) {
    int h = gid - nWT - nW2T - nWb;
    float s1 = 0.f, s2 = 0.f;
    for (int i = 0; i < DD; ++i) {
      s1 += lk1[h * DD + i] * lv1[h * DD + i];
      s2 += lk2[h * DD + i] * lv2[h * DD + i];
    }
    float lambda_init = 0.8f - 0.6f * __expf(-0.3f);
    float lam = __expf(s1) - __expf(s2) + lambda_init;
    lamS[h] = 1.0f - lam;                             // attn = (1-lambda)*A
  }
}

// ---------------------------------------------------------------------------
// fused qkv projection + per-head linear attention
// grid: 1024 blocks (2 batch elements each), 512 threads (8 waves)
// LDS layout (141 KB total, 1 block/CU = 8 waves/CU):
//   Xs  [128][392] bf16 @ 0       (100352 B)  staged x for 2 batches
//   Wt dbuf 2x[96][64] @ 100352   ( 24576 B)  swizzled weights (global_load_lds)
//     reused post-GEMM: StK/StV [2 batches][32][72] transposed fk / fv
//   Sq  [128][56] @ 124928        ( 14336 B)  q rows (row-major)
//   At  2x[32][40] @ 139264       (  5120 B)  attn^T per batch
// ---------------------------------------------------------------------------
__global__ __launch_bounds__(512, 2) void qkv_attn_kernel(
    const float* __restrict__ x,
    const unsigned short* __restrict__ WT,
    const float* __restrict__ Wb,
    const float* __restrict__ lamS,
    unsigned short* __restrict__ O)
{
  __shared__ __align__(16) char smem[144384];
  unsigned short* Xs       = (unsigned short*)smem;              // [128][392]
  unsigned short* WtRegion = (unsigned short*)(smem + 100352);   // dbuf / St region
  unsigned short* Sq       = (unsigned short*)(smem + 124928);   // [128][56]
  unsigned short* AtBase   = (unsigned short*)(smem + 139264);   // 2x[32][40]

  const int tid  = threadIdx.x;
  const int lane = tid & 63;
  const int wave = tid >> 6;     // 0..7
  const int quad = lane >> 4;
  const int l15  = lane & 15;
  const int rg   = wave >> 1;    // GEMM row group (32 rows each)
  const int ch   = wave & 1;     // GEMM col half (48 cols each)
  const int bb   = wave >> 2;    // batch within block
  const int ww   = wave & 3;     // wave index within batch

  // async weight staging: 96x64 bf16 chunk = 768 x 16B slots, linear LDS dest,
  // XOR-swizzled global source (seg ^ (row&7)) so swizzled reads are 2-way max.
  auto stage_wt = [&](const unsigned short* src0, char* ldsb) {
    {
      int c = tid >> 3, sg = tid & 7;
      const unsigned short* sp = src0 + c * CC + ((sg ^ (c & 7)) << 3);
      __builtin_amdgcn_global_load_lds((gu32c*)(const void*)sp,
          (lu32*)(void*)(ldsb + (tid & ~63) * 16), 16, 0, 0);
    }
    if (tid < 256) {                                   // wave-uniform branch
      int p = 512 + tid;
      int c = p >> 3, sg = p & 7;
      const unsigned short* sp = src0 + c * CC + ((sg ^ (c & 7)) << 3);
      __builtin_amdgcn_global_load_lds((gu32c*)(const void*)sp,
          (lu32*)(void*)(ldsb + 8192 + (tid & ~63) * 16), 16, 0, 0);
    }
  };

  // prefetch head-0 chunk-0 weights; stage x for 2 batches fp32->bf16
  stage_wt(WT, (char*)WtRegion);
  {
    const float* xb = x + (size_t)blockIdx.x * (2 * NN * CC);
    #pragma unroll
    for (int it = 0; it < 24; ++it) {
      int i = it * 512 + tid;          // 0..12287 float4 slots (128 rows x 96)
      int row = i / 96, c4 = i % 96;
      float4 v = *(const float4*)(xb + row * CC + c4 * 4);
      ushort4 o;
      o.x = f2bf(v.x); o.y = f2bf(v.y); o.z = f2bf(v.z); o.w = f2bf(v.w);
      *(ushort4*)(Xs + row * 392 + c4 * 4) = o;
    }
  }
  __syncthreads();   // Xs staged + chunk0 weights landed (vmcnt(0) at barrier)

  for (int h = 0; h < HH; ++h) {
    const unsigned short* Wh = WT + (size_t)h * (96 * CC);

    f32x4 acc[2][3];
    #pragma unroll
    for (int mt = 0; mt < 2; ++mt)
      #pragma unroll
      for (int t = 0; t < 3; ++t) acc[mt][t] = (f32x4){0.f, 0.f, 0.f, 0.f};

    // ---- GEMM: 128 rows x 96 cols over K=384; wave tile 32x48 ----
    for (int kc = 0; kc < 6; ++kc) {
      if (kc < 5)
        stage_wt(Wh + (kc + 1) * 64, (char*)WtRegion + ((kc + 1) & 1) * 12288);
      const unsigned short* Wt = WtRegion + (kc & 1) * 6144;
      __builtin_amdgcn_s_setprio(1);
      #pragma unroll
      for (int step = 0; step < 2; ++step) {
        const int kk = step * 32 + quad * 8;
        const int sw = (((step * 4 + quad) ^ (l15 & 7)) << 3);
        short8 a0 = *(const short8*)(Xs + (rg * 32 +      l15) * 392 + kc * 64 + kk);
        short8 a1 = *(const short8*)(Xs + (rg * 32 + 16 + l15) * 392 + kc * 64 + kk);
        #pragma unroll
        for (int t = 0; t < 3; ++t) {
          short8 bfr = *(const short8*)(Wt + (ch * 48 + t * 16 + l15) * 64 + sw);
          acc[0][t] = MFMA_BF16(a0, bfr, acc[0][t]);
          acc[1][t] = MFMA_BF16(a1, bfr, acc[1][t]);
        }
      }
      __builtin_amdgcn_s_setprio(0);
      __syncthreads();     // drains prefetch (vmcnt) + hands buffer over
    }

    // ---- epilogue: q -> Sq (row-major, *scale); fk/fv -> StK/StV transposed
    //      packed b64 writes: [i|e][n] stride 72 (conflict-free b128 reads) ----
    {
      unsigned short* StK = WtRegion + bb * 4608;   // [32][72] (overlays Wt dbuf)
      unsigned short* StV = StK + 2304;
      #pragma unroll
      for (int mt = 0; mt < 2; ++mt) {
        const int rowb = rg * 32 + mt * 16 + quad * 4;   // block row (r=0)
        const int nloc = rowb & 63;
        #pragma unroll
        for (int t = 0; t < 3; ++t) {
          const int c0 = ch * 48 + t * 16;
          const int c  = c0 + l15;
          float bias = Wb[h * 96 + c];
          if (c0 < 32) {                       // q: scale, row-major scalar
            #pragma unroll
            for (int r = 0; r < 4; ++r) {
              float v = (acc[mt][t][r] + bias) * 0.17677669529663689f;
              Sq[(rowb + r) * 56 + c] = f2bf(v);
            }
          } else {                             // k/v: ELU+1, transposed pack4
            us4 pk;
            #pragma unroll
            for (int r = 0; r < 4; ++r) {
              float v = acc[mt][t][r] + bias;
              v = (v >= 0.f) ? (v + 1.f) : __expf(v);
              pk[r] = f2bf(v);
            }
            if (c0 < 64) *(us4*)(StK + (c0 - 32 + l15) * 72 + nloc) = pk;
            else         *(us4*)(StV + (c0 - 64 + l15) * 72 + nloc) = pk;
          }
        }
      }
    }
    __syncthreads();

    // ---- A[i][e] = sum_n fk[n][i]*fv[n][e]; At[e][i] = (1-lam)*gauss*A ----
    {
      const unsigned short* StK = WtRegion + bb * 4608;
      const unsigned short* StV = StK + 2304;
      const int i0 = (ww & 1) * 16;
      const int e0 = (ww >> 1) * 16;
      f32x4 accA = (f32x4){0.f, 0.f, 0.f, 0.f};
      #pragma unroll
      for (int n0 = 0; n0 < 64; n0 += 32) {
        short8 afr = *(const short8*)(StK + (i0 + l15) * 72 + n0 + quad * 8);
        short8 bfr = *(const short8*)(StV + (e0 + l15) * 72 + n0 + quad * 8);
        accA = MFMA_BF16(afr, bfr, accA);
      }
      const float lsc = lamS[h];
      unsigned short* At = AtBase + bb * 1280;
      const int e = e0 + l15;
      us4 pk;
      #pragma unroll
      for (int r = 0; r < 4; ++r) {
        int i = i0 + quad * 4 + r;
        float diff = (float)(i - e);
        pk[r] = f2bf(accA[r] * lsc * __expf(-2.0f * diff * diff));  // sigma=0.5
      }
      *(us4*)(At + e * 40 + i0 + quad * 4) = pk;     // At[e][i], pack over i
    }
    __syncthreads();

    // prefetch next head's chunk-0 weights under the out-phase
    if (h < HH - 1) stage_wt(WT + (size_t)(h + 1) * (96 * CC), (char*)WtRegion);

    // ---- out = q @ attn  (64x32 per batch) -> O[b,n, h*32+e] bf16 ----
    {
      const unsigned short* At = AtBase + bb * 1280;
      short8 aq = *(const short8*)(Sq + (wave * 16 + l15) * 56 + quad * 8);
      const size_t bg = (size_t)blockIdx.x * 2 + bb;
      const int nw0 = ww * 16 + quad * 4;
      #pragma unroll
      for (int t2 = 0; t2 < 2; ++t2) {
        short8 bA = *(const short8*)(At + (t2 * 16 + l15) * 40 + quad * 8);
        f32x4 accO = MFMA_BF16(aq, bA, ((f32x4){0.f, 0.f, 0.f, 0.f}));
        #pragma unroll
        for (int r = 0; r < 4; ++r) {
          O[(bg * NN + nw0 + r) * CC + h * DD + t2 * 16 + l15] = f2bf(accO[r]);
        }
      }
    }
    __syncthreads();   // drains chunk-0 prefetch before next head's GEMM
  }
}

// ---------------------------------------------------------------------------
// projection GEMM: out[131072][384] = O[131072][384] @ proj_w + proj_b (fp32)
// 128x128 tiles, 4 waves of 64x64; async swizzled global_load_lds double
// buffer (1 barrier/chunk); bijective XCD swizzle so the 3 column-blocks
// sharing an O-panel land on the same XCD's L2.
// ---------------------------------------------------------------------------
__global__ __launch_bounds__(256, 2) void proj_kernel(
    const unsigned short* __restrict__ O,
    const unsigned short* __restrict__ W2T,
    const float* __restrict__ proj_b,
    float* __restrict__ out)
{
  __shared__ __align__(16) char smem[65536];   // dbuf: 2 x (As 16K | Bs 16K)

  const int tid  = threadIdx.x;
  const int lane = tid & 63, wave = tid >> 6;
  const int quad = lane >> 4, l15 = lane & 15;
  const int mw = (wave >> 1) * 64, nw = (wave & 1) * 64;

  const int lid = blockIdx.x;                       // 0..3071
  const int nid = (lid & 7) * 384 + (lid >> 3);     // XCD-chunked bijection
  const int bm = nid / 3, bn = nid % 3;
  const int m0 = bm * 128, n0 = bn * 128;

  auto stg = [&](int kc, int sel) {
    char* ab = smem + sel * 32768;
    #pragma unroll
    for (int i = 0; i < 4; ++i) {
      int p = i * 256 + tid;                        // 1024 slots x 16B per tile
      int row = p >> 3, sg = p & 7;
      int sw = ((sg ^ (row & 7)) << 3);
      const unsigned short* sa = O   + (size_t)(m0 + row) * CC + kc * 64 + sw;
      const unsigned short* sb = W2T + (size_t)(n0 + row) * CC + kc * 64 + sw;
      int ub = (p & ~63) * 16;
      __builtin_amdgcn_global_load_lds((gu32c*)(const void*)sa,
          (lu32*)(void*)(ab + ub), 16, 0, 0);
      __builtin_amdgcn_global_load_lds((gu32c*)(const void*)sb,
          (lu32*)(void*)(ab + 16384 + ub), 16, 0, 0);
    }
  };

  f32x4 acc[4][4];
  #pragma unroll
  for (int i = 0; i < 4; ++i)
    #pragma unroll
    for (int j = 0; j < 4; ++j) acc[i][j] = (f32x4){0.f, 0.f, 0.f, 0.f};

  stg(0, 0);
  __syncthreads();
  for (int kc = 0; kc < 6; ++kc) {
    if (kc < 5) stg(kc + 1, (kc + 1) & 1);
    const unsigned short* As = (const unsigned short*)(smem + (kc & 1) * 32768);
    const unsigned short* Bs = As + 8192;
    __builtin_amdgcn_s_setprio(1);
    #pragma unroll
    for (int step = 0; step < 2; ++step) {
      const int sw = (((step * 4 + quad) ^ (l15 & 7)) << 3);
      short8 af[4], bf_[4];
      #pragma unroll
      for (int t = 0; t < 4; ++t) {
        af[t]  = *(const short8*)(As + (mw + t * 16 + l15) * 64 + sw);
        bf_[t] = *(const short8*)(Bs + (nw + t * 16 + l15) * 64 + sw);
      }
      #pragma unroll
      for (int i = 0; i < 4; ++i)
        #pragma unroll
        for (int j = 0; j < 4; ++j)
          acc[i][j] = MFMA_BF16(af[i], bf_[j], acc[i][j]);
    }
    __builtin_amdgcn_s_setprio(0);
    __syncthreads();
  }

  #pragma unroll
  for (int j = 0; j < 4; ++j) {
    int col = n0 + nw + j * 16 + l15;
    float bias = proj_b[col];
    #pragma unroll
    for (int i = 0; i < 4; ++i) {
      int row0 = m0 + mw + i * 16 + quad * 4;
      #pragma unroll
      for (int r = 0; r < 4; ++r) {
        out[(size_t)(row0 + r) * CC + col] = acc[i][j][r] + bias;
      }
    }
  }
}

// ---------------------------------------------------------------------------
extern "C" void kernel_launch(void* const* d_in, const int* in_sizes, int n_in,
                              void* d_out, int out_size, void* d_ws, size_t ws_size,
                              hipStream_t stream) {
  const float* x      = (const float*)d_in[0];
  const float* qkv_w  = (const float*)d_in[1];
  const float* qkv_b  = (const float*)d_in[2];
  const float* proj_w = (const float*)d_in[3];
  const float* proj_b = (const float*)d_in[4];
  const float* lk1    = (const float*)d_in[5];
  const float* lv1    = (const float*)d_in[6];
  const float* lk2    = (const float*)d_in[7];
  const float* lv2    = (const float*)d_in[8];

  char* ws = (char*)d_ws;                 // needs ~101.9 MB of workspace
  unsigned short* O   = (unsigned short*)(ws + WS_O);
  unsigned short* WT  = (unsigned short*)(ws + WS_WT);
  unsigned short* W2T = (unsigned short*)(ws + WS_W2T);
  float* Wb           = (float*)(ws + WS_WB);
  float* lamS         = (float*)(ws + WS_LAM);

  setup_kernel<<<2309, 256, 0, stream>>>(qkv_w, qkv_b, proj_w,
                                         lk1, lv1, lk2, lv2,
                                         WT, W2T, Wb, lamS);
  qkv_attn_kernel<<<1024, 512, 0, stream>>>(x, WT, Wb, lamS, O);
  proj_kernel<<<3072, 256, 0, stream>>>(O, W2T, proj_b, (float*)d_out);
}

// Round 2
// 590.744 us; speedup vs baseline: 1.4878x; 1.0541x over previous
//
#include <hip/hip_runtime.h>
#include <hip/hip_bf16.h>
#include <math.h>

// ---------------------------------------------------------------------------
// WindowAttention (dual-lambda linear attention) for MI355X / gfx950
//   B=2048, N=64 tokens, C=384, H=12 heads, d=32
//   Single fused kernel: qkv GEMM (x held in registers) + per-head linear
//   attention + output projection, all in one block per 2 batch elements.
//   O intermediate lives in LDS (reusing the x staging buffer) -- no global
//   O round-trip, no separate proj kernel.
// ---------------------------------------------------------------------------

typedef __attribute__((ext_vector_type(8))) short short8;   // 8 x bf16
typedef __attribute__((ext_vector_type(4))) float f32x4;
typedef __attribute__((ext_vector_type(4))) unsigned short us4;

typedef const __attribute__((address_space(1))) unsigned int gu32c;
typedef __attribute__((address_space(3))) unsigned int lu32;

#define MFMA_BF16(A,B,C) __builtin_amdgcn_mfma_f32_16x16x32_bf16(A,B,C,0,0,0)

__device__ __forceinline__ unsigned short f2bf(float f) {
  unsigned int u = __float_as_uint(f);
  u += 0x7FFFu + ((u >> 16) & 1u);            // round-to-nearest-even
  return (unsigned short)(u >> 16);
}

#define BB 2048
#define NN 64
#define CC 384
#define HH 12
#define DD 32

// workspace byte offsets (total ~1.2 MB -- O intermediate eliminated)
#define WS_WT   0                         // bf16 [12][96][384] = 884736 B
#define WS_W2T  884736                    // bf16 [384][384]    = 294912 B
#define WS_WB   1179648                   // f32  [12][96]      =   4608 B
#define WS_LAM  1184256                   // f32  [12]          =     48 B

// ---------------------------------------------------------------------------
// setup: repack qkv_w -> WT[h][c][k] (c: 0-31 q, 32-63 k, 64-95 v),
//        proj_w -> W2T[n][k], biases -> Wb[h][c], lamS[h] = 1 - lambda_full
// ---------------------------------------------------------------------------
__global__ void setup_kernel(const float* __restrict__ qkv_w,
                             const float* __restrict__ qkv_b,
                             const float* __restrict__ proj_w,
                             const float* __restrict__ lk1, const float* __restrict__ lv1,
                             const float* __restrict__ lk2, const float* __restrict__ lv2,
                             unsigned short* __restrict__ WT,
                             unsigned short* __restrict__ W2T,
                             float* __restrict__ Wb,
                             float* __restrict__ lamS)
{
  const int nWT  = HH * 96 * CC;   // 442368
  const int nW2T = CC * CC;        // 147456
  const int nWb  = HH * 96;        // 1152
  int gid = blockIdx.x * 256 + threadIdx.x;
  if (gid < nWT) {
    int h = gid / (96 * CC);
    int r = gid % (96 * CC);
    int c = r / CC;
    int k = r % CC;
    int col = (c >> 5) * CC + h * DD + (c & 31);      // q/k/v block, head, dim
    WT[gid] = f2bf(qkv_w[(size_t)k * (3 * CC) + col]);
  } else if (gid < nWT + nW2T) {
    int j = gid - nWT;
    int n = j / CC, k = j % CC;
    W2T[j] = f2bf(proj_w[(size_t)k * CC + n]);
  } else if (gid < nWT + nW2T + nWb) {
    int j = gid - nWT - nW2T;
    int h = j / 96, c = j % 96;
    Wb[j] = qkv_b[(c >> 5) * CC + h * DD + (c & 31)];
  } else if (gid < nWT + nW2T + nWb + HH) {
    int h = gid - nWT - nW2T - nWb;
    float s1 = 0.f, s2 = 0.f;
    for (int i = 0; i < DD; ++i) {
      s1 += lk1[h * DD + i] * lv1[h * DD + i];
      s2 += lk2[h * DD + i] * lv2[h * DD + i];
    }
    float lambda_init = 0.8f - 0.6f * __expf(-0.3f);
    float lam = __expf(s1) - __expf(s2) + lambda_init;
    lamS[h] = 1.0f - lam;                             // attn = (1-lambda)*A
  }
}

// ---------------------------------------------------------------------------
// fused qkv + attention + projection
// grid: 1024 blocks (2 batch elements each), 512 threads (8 waves)
// LDS layout (141 KB, 1 block/CU):
//   OX  [128][392] bf16 @ 0       (100352 B)  x during setup -> O after heads
//   WtRegion @ 100352             ( 24576 B)  weight dbuf (qkv chunks / W2T
//     chunks); overlaid per-head by StK/StV [2][32][72] transposed fk/fv
//   Sq  [128][56] @ 124928        ( 14336 B)  q rows
//   At  2x[32][40] @ 139264       (  5120 B)  attn^T per batch
// x A-fragments are held in registers (xa[2][12], 96 VGPR) -- loaded once,
// reused across all 12 heads; frees OX for the O intermediate.
// ---------------------------------------------------------------------------
__global__ __launch_bounds__(512, 2) void fused_kernel(
    const float* __restrict__ x,
    const unsigned short* __restrict__ WT,
    const float* __restrict__ Wb,
    const float* __restrict__ lamS,
    const unsigned short* __restrict__ W2T,
    const float* __restrict__ proj_b,
    float* __restrict__ out)
{
  __shared__ __align__(16) char smem[144384];
  unsigned short* OX       = (unsigned short*)smem;              // [128][392]
  unsigned short* WtRegion = (unsigned short*)(smem + 100352);   // dbuf / St
  unsigned short* Sq       = (unsigned short*)(smem + 124928);   // [128][56]
  unsigned short* AtBase   = (unsigned short*)(smem + 139264);   // 2x[32][40]

  const int tid  = threadIdx.x;
  const int lane = tid & 63;
  const int wave = tid >> 6;     // 0..7
  const int quad = lane >> 4;
  const int l15  = lane & 15;
  const int rg   = wave >> 1;    // GEMM row group (32 rows each)
  const int ch   = wave & 1;     // GEMM col half (48 cols each)
  const int bb   = wave >> 2;    // batch within block
  const int ww   = wave & 3;     // wave index within batch

  // qkv weight staging: 96x64 bf16 chunk = 768 x 16B slots, linear LDS dest,
  // XOR-swizzled global source (seg ^ (row&7)) so swizzled reads are free.
  auto stage_wt = [&](const unsigned short* src0, char* ldsb) {
    {
      int c = tid >> 3, sg = tid & 7;
      const unsigned short* sp = src0 + c * CC + ((sg ^ (c & 7)) << 3);
      __builtin_amdgcn_global_load_lds((gu32c*)(const void*)sp,
          (lu32*)(void*)(ldsb + (tid & ~63) * 16), 16, 0, 0);
    }
    if (tid < 256) {                                   // wave-uniform branch
      int p = 512 + tid;
      int c = p >> 3, sg = p & 7;
      const unsigned short* sp = src0 + c * CC + ((sg ^ (c & 7)) << 3);
      __builtin_amdgcn_global_load_lds((gu32c*)(const void*)sp,
          (lu32*)(void*)(ldsb + 8192 + (tid & ~63) * 16), 16, 0, 0);
    }
  };

  // proj weight staging: [192 n][32 k] chunk = 768 x 16B slots (4 slots/row),
  // slot swizzle (sg ^ ((row>>1)&3)) -> conflict-free b128 reads.
  auto stage_w2 = [&](int nh, int kc, int sel) {
    char* ldsb = (char*)WtRegion + sel * 12288;
    {
      int row = tid >> 2, sg = tid & 3;
      const unsigned short* sp = W2T + (size_t)(nh * 192 + row) * CC + kc * 32
                                 + ((sg ^ ((row >> 1) & 3)) << 3);
      __builtin_amdgcn_global_load_lds((gu32c*)(const void*)sp,
          (lu32*)(void*)(ldsb + (tid & ~63) * 16), 16, 0, 0);
    }
    if (tid < 256) {
      int p = 512 + tid;
      int row = p >> 2, sg = p & 3;
      const unsigned short* sp = W2T + (size_t)(nh * 192 + row) * CC + kc * 32
                                 + ((sg ^ ((row >> 1) & 3)) << 3);
      __builtin_amdgcn_global_load_lds((gu32c*)(const void*)sp,
          (lu32*)(void*)(ldsb + (p & ~63) * 16), 16, 0, 0);
    }
  };

  // prefetch head-0 chunk-0 weights; stage x for 2 batches fp32->bf16
  stage_wt(WT, (char*)WtRegion);
  {
    const float* xb = x + (size_t)blockIdx.x * (2 * NN * CC);
    #pragma unroll
    for (int it = 0; it < 24; ++it) {
      int i = it * 512 + tid;          // 12288 float4 slots (128 rows x 96)
      int row = i / 96, c4 = i % 96;
      float4 v = *(const float4*)(xb + row * CC + c4 * 4);
      ushort4 o;
      o.x = f2bf(v.x); o.y = f2bf(v.y); o.z = f2bf(v.z); o.w = f2bf(v.w);
      *(ushort4*)(OX + row * 392 + c4 * 4) = o;
    }
  }
  __syncthreads();   // x staged + chunk0 weights landed

  // ---- hoist x A-fragments into registers: 2 rows/lane x 384 k = 96 VGPR.
  //      statically indexed (unrolled) so they stay in registers (rule #20).
  short8 xa[2][12];
  #pragma unroll
  for (int mt = 0; mt < 2; ++mt)
    #pragma unroll
    for (int s = 0; s < 12; ++s)       // s = kc*2+step, col = s*32 + quad*8
      xa[mt][s] = *(const short8*)(OX + (rg * 32 + mt * 16 + l15) * 392
                                   + s * 32 + quad * 8);

  for (int h = 0; h < HH; ++h) {
    const unsigned short* Wh = WT + (size_t)h * (96 * CC);

    f32x4 acc[2][3];
    #pragma unroll
    for (int mt = 0; mt < 2; ++mt)
      #pragma unroll
      for (int t = 0; t < 3; ++t) acc[mt][t] = (f32x4){0.f, 0.f, 0.f, 0.f};

    // ---- GEMM: 128 rows x 96 cols over K=384; A from registers ----
    #pragma unroll
    for (int kc = 0; kc < 6; ++kc) {
      if (kc < 5)
        stage_wt(Wh + (kc + 1) * 64, (char*)WtRegion + ((kc + 1) & 1) * 12288);
      const unsigned short* Wt = WtRegion + (kc & 1) * 6144;
      __builtin_amdgcn_s_setprio(1);
      #pragma unroll
      for (int step = 0; step < 2; ++step) {
        const int sw = (((step * 4 + quad) ^ (l15 & 7)) << 3);
        #pragma unroll
        for (int t = 0; t < 3; ++t) {
          short8 bfr = *(const short8*)(Wt + (ch * 48 + t * 16 + l15) * 64 + sw);
          acc[0][t] = MFMA_BF16(xa[0][kc * 2 + step], bfr, acc[0][t]);
          acc[1][t] = MFMA_BF16(xa[1][kc * 2 + step], bfr, acc[1][t]);
        }
      }
      __builtin_amdgcn_s_setprio(0);
      __syncthreads();     // drains prefetch + hands buffer over
    }

    // ---- epilogue: q -> Sq (*scale); fk/fv -> StK/StV transposed pack4 ----
    {
      unsigned short* StK = WtRegion + bb * 4608;   // [32][72], overlays dbuf
      unsigned short* StV = StK + 2304;
      #pragma unroll
      for (int mt = 0; mt < 2; ++mt) {
        const int rowb = rg * 32 + mt * 16 + quad * 4;
        const int nloc = rowb & 63;
        #pragma unroll
        for (int t = 0; t < 3; ++t) {
          const int c0 = ch * 48 + t * 16;
          const int c  = c0 + l15;
          float bias = Wb[h * 96 + c];
          if (c0 < 32) {                       // q: scale, row-major scalar
            #pragma unroll
            for (int r = 0; r < 4; ++r) {
              float v = (acc[mt][t][r] + bias) * 0.17677669529663689f;
              Sq[(rowb + r) * 56 + c] = f2bf(v);
            }
          } else {                             // k/v: ELU+1, transposed pack4
            us4 pk;
            #pragma unroll
            for (int r = 0; r < 4; ++r) {
              float v = acc[mt][t][r] + bias;
              v = (v >= 0.f) ? (v + 1.f) : __expf(v);
              pk[r] = f2bf(v);
            }
            if (c0 < 64) *(us4*)(StK + (c0 - 32 + l15) * 72 + nloc) = pk;
            else         *(us4*)(StV + (c0 - 64 + l15) * 72 + nloc) = pk;
          }
        }
      }
    }
    __syncthreads();

    // ---- A[i][e] = sum_n fk[n][i]*fv[n][e]; At[e][i] = (1-lam)*gauss*A ----
    {
      const unsigned short* StK = WtRegion + bb * 4608;
      const unsigned short* StV = StK + 2304;
      const int i0 = (ww & 1) * 16;
      const int e0 = (ww >> 1) * 16;
      f32x4 accA = (f32x4){0.f, 0.f, 0.f, 0.f};
      #pragma unroll
      for (int n0 = 0; n0 < 64; n0 += 32) {
        short8 afr = *(const short8*)(StK + (i0 + l15) * 72 + n0 + quad * 8);
        short8 bfr = *(const short8*)(StV + (e0 + l15) * 72 + n0 + quad * 8);
        accA = MFMA_BF16(afr, bfr, accA);
      }
      const float lsc = lamS[h];
      unsigned short* At = AtBase + bb * 1280;
      const int e = e0 + l15;
      us4 pk;
      #pragma unroll
      for (int r = 0; r < 4; ++r) {
        int i = i0 + quad * 4 + r;
        float diff = (float)(i - e);
        pk[r] = f2bf(accA[r] * lsc * __expf(-2.0f * diff * diff)); // sigma=0.5
      }
      *(us4*)(At + e * 40 + i0 + quad * 4) = pk;     // At[e][i]
    }
    __syncthreads();

    // prefetch under the out-phase: next head's chunk-0, or first proj chunk
    if (h < HH - 1) stage_wt(WT + (size_t)(h + 1) * (96 * CC), (char*)WtRegion);
    else            stage_w2(0, 0, 0);

    // ---- out = q @ attn  (64x32 per batch) -> O in LDS (OX region) ----
    {
      const unsigned short* At = AtBase + bb * 1280;
      short8 aq = *(const short8*)(Sq + (wave * 16 + l15) * 56 + quad * 8);
      const int lrow = wave * 16 + quad * 4;          // local O row
      #pragma unroll
      for (int t2 = 0; t2 < 2; ++t2) {
        short8 bA = *(const short8*)(At + (t2 * 16 + l15) * 40 + quad * 8);
        f32x4 accO = MFMA_BF16(aq, bA, ((f32x4){0.f, 0.f, 0.f, 0.f}));
        #pragma unroll
        for (int r = 0; r < 4; ++r)
          OX[(lrow + r) * 392 + h * DD + t2 * 16 + l15] = f2bf(accO[r]);
      }
    }
    __syncthreads();   // drains prefetch; O writes visible before next phase
  }

  // ---------------------------------------------------------------------
  // projection: out[128][384] = O_lds[128][384] @ W2T^T + proj_b  (fp32)
  // N in 2 halves of 192; wave tile 32 rows x 96 cols; K chunks of 32,
  // double-buffered in WtRegion (2 x 12288 B).
  // ---------------------------------------------------------------------
  {
    const int rg2 = wave >> 1;       // 0..3: row group (32 rows)
    const int cg2 = wave & 1;        // 0..1: col group within 192-col half
    const size_t rowg0 = (size_t)blockIdx.x * 128 + rg2 * 32;

    for (int nh = 0; nh < 2; ++nh) {
      f32x4 acc2[2][6];
      #pragma unroll
      for (int mt = 0; mt < 2; ++mt)
        #pragma unroll
        for (int t = 0; t < 6; ++t) acc2[mt][t] = (f32x4){0.f, 0.f, 0.f, 0.f};

      for (int kc = 0; kc < 12; ++kc) {
        if (kc < 11)      stage_w2(nh, kc + 1, (kc + 1) & 1);
        else if (nh == 0) stage_w2(1, 0, 0);
        const unsigned short* Wp = WtRegion + (kc & 1) * 6144;
        __builtin_amdgcn_s_setprio(1);
        short8 a0 = *(const short8*)(OX + (rg2 * 32 +      l15) * 392
                                     + kc * 32 + quad * 8);
        short8 a1 = *(const short8*)(OX + (rg2 * 32 + 16 + l15) * 392
                                     + kc * 32 + quad * 8);
        #pragma unroll
        for (int t = 0; t < 6; ++t) {
          const int row = cg2 * 96 + t * 16 + l15;
          short8 b = *(const short8*)(Wp + row * 32
                                      + ((quad ^ ((row >> 1) & 3)) << 3));
          acc2[0][t] = MFMA_BF16(a0, b, acc2[0][t]);
          acc2[1][t] = MFMA_BF16(a1, b, acc2[1][t]);
        }
        __builtin_amdgcn_s_setprio(0);
        __syncthreads();
      }

      #pragma unroll
      for (int t = 0; t < 6; ++t) {
        const int col = nh * 192 + cg2 * 96 + t * 16 + l15;
        const float bias = proj_b[col];
        #pragma unroll
        for (int mt = 0; mt < 2; ++mt) {
          const size_t row0 = rowg0 + mt * 16 + quad * 4;
          #pragma unroll
          for (int r = 0; r < 4; ++r)
            out[(row0 + r) * CC + col] = acc2[mt][t][r] + bias;
        }
      }
    }
  }
}

// ---------------------------------------------------------------------------
extern "C" void kernel_launch(void* const* d_in, const int* in_sizes, int n_in,
                              void* d_out, int out_size, void* d_ws, size_t ws_size,
                              hipStream_t stream) {
  const float* x      = (const float*)d_in[0];
  const float* qkv_w  = (const float*)d_in[1];
  const float* qkv_b  = (const float*)d_in[2];
  const float* proj_w = (const float*)d_in[3];
  const float* proj_b = (const float*)d_in[4];
  const float* lk1    = (const float*)d_in[5];
  const float* lv1    = (const float*)d_in[6];
  const float* lk2    = (const float*)d_in[7];
  const float* lv2    = (const float*)d_in[8];

  char* ws = (char*)d_ws;                 // needs ~1.2 MB of workspace
  unsigned short* WT  = (unsigned short*)(ws + WS_WT);
  unsigned short* W2T = (unsigned short*)(ws + WS_W2T);
  float* Wb           = (float*)(ws + WS_WB);
  float* lamS         = (float*)(ws + WS_LAM);

  setup_kernel<<<2309, 256, 0, stream>>>(qkv_w, qkv_b, proj_w,
                                         lk1, lv1, lk2, lv2,
                                         WT, W2T, Wb, lamS);
  fused_kernel<<<1024, 512, 0, stream>>>(x, WT, Wb, lamS, W2T, proj_b,
                                         (float*)d_out);
}